// Round 1
// baseline (3159.243 us; speedup 1.0000x reference)
//
#include <hip/hip_runtime.h>
#include <stdint.h>

#define L_SEQ 2048
#define DM 1024
#define NH 16
#define DFF 4096
#define NB 4
#define ROWS (NB * L_SEQ)   // 8192

typedef __attribute__((ext_vector_type(8))) __bf16 bf16x8;
typedef __attribute__((ext_vector_type(4))) float f32x4;

__device__ __forceinline__ float bf2f(unsigned short u) {
  union { unsigned int i; float f; } x; x.i = ((unsigned int)u) << 16; return x.f;
}
__device__ __forceinline__ unsigned short f2bf(float f) {
  union { float f; unsigned int i; } x; x.f = f;
  unsigned int r = x.i + 0x7FFFu + ((x.i >> 16) & 1u);
  return (unsigned short)(r >> 16);
}

typedef __attribute__((address_space(3))) void lds_void;
typedef const __attribute__((address_space(1))) void gbl_void;

// Forced global_load_lds (gfx950): lane i's 16 bytes land at base + i*16.
__device__ __forceinline__ void stage16(const void* g, void* ldsbase) {
  __builtin_amdgcn_global_load_lds((gbl_void*)g, (lds_void*)ldsbase, 16, 0, 0);
}

// ---------------------------------------------------------------------------
// Legacy 128x128 kernel — kept for the final projection (N=128 only).
// ---------------------------------------------------------------------------
__global__ __launch_bounds__(256)
void gemm_bt(const unsigned short* __restrict__ A,
             const unsigned short* __restrict__ B,
             const float* __restrict__ bias,
             unsigned short* __restrict__ C16,
             float* __restrict__ C32,
             int K, int lda, int ldc, int n_limit, int act)
{
  __shared__ __attribute__((aligned(16))) unsigned short As[128 * 32];
  __shared__ __attribute__((aligned(16))) unsigned short Bs[128 * 32];
  const int tid  = threadIdx.x;
  const int wave = tid >> 6, lane = tid & 63;
  const int wm = (wave & 1) << 6, wn = (wave >> 1) << 6;
  const int l16 = lane & 15, quad = lane >> 4;

  const unsigned short* Ab = A + (size_t)blockIdx.x * 128 * lda;
  const unsigned short* Bb = B + (size_t)blockIdx.y * 128 * K;

  const int srow = (wave << 4) + (lane >> 2);   // 0..63
  const int scol = (lane & 3) << 3;

  f32x4 acc[4][4] = {};

  for (int k0 = 0; k0 < K; k0 += 32) {
    const size_t aoff = (size_t)srow * lda + k0 + scol;
    const size_t boff = (size_t)srow * K   + k0 + scol;
    stage16(Ab + aoff,                    &As[(wave * 16) * 32]);
    stage16(Ab + aoff + (size_t)64 * lda, &As[(wave * 16 + 64) * 32]);
    stage16(Bb + boff,                    &Bs[(wave * 16) * 32]);
    stage16(Bb + boff + (size_t)64 * K,   &Bs[(wave * 16 + 64) * 32]);
    __syncthreads();

    bf16x8 af[4], bfr[4];
#pragma unroll
    for (int mi = 0; mi < 4; mi++)
      af[mi] = *(const bf16x8*)&As[(wm + mi * 16 + l16) * 32 + quad * 8];
#pragma unroll
    for (int ni = 0; ni < 4; ni++)
      bfr[ni] = *(const bf16x8*)&Bs[(wn + ni * 16 + l16) * 32 + quad * 8];
#pragma unroll
    for (int mi = 0; mi < 4; mi++)
#pragma unroll
      for (int ni = 0; ni < 4; ni++)
        acc[mi][ni] = __builtin_amdgcn_mfma_f32_16x16x32_bf16(af[mi], bfr[ni], acc[mi][ni], 0, 0, 0);
    __syncthreads();
  }

  const int row0 = (int)blockIdx.x * 128 + wm + quad * 4;
  const int col0 = (int)blockIdx.y * 128 + wn + l16;
#pragma unroll
  for (int ni = 0; ni < 4; ni++) {
    const int col = col0 + ni * 16;
    if (col >= n_limit) continue;
    const float bv = bias ? bias[col] : 0.0f;
    const bool sig = (act == 2) || (act == 3 && col < 2048);
#pragma unroll
    for (int mi = 0; mi < 4; mi++) {
#pragma unroll
      for (int r = 0; r < 4; r++) {
        const int row = row0 + mi * 16 + r;
        float v = acc[mi][ni][r] + bv;
        if (act == 1) v = fmaxf(v, 0.0f);
        else if (sig) v = 1.0f / (1.0f + __expf(-v));
        if (C32) C32[(size_t)row * ldc + col] = v;
        if (C16) C16[(size_t)row * ldc + col] = f2bf(v);
      }
    }
  }
}

// ===========================================================================
// 256x256x64 8-phase pipelined GEMM (T2 conflict-free LDS + T3/T4 counted
// vmcnt + T5 setprio + T1 XCD swizzle). C = A[8192,K] * B[N,K]^T.
// LDS: 2 buffers x (A 32KB + B 32KB) = 128 KiB. 8 waves (2M x 4N).
// LDS layout is FRAGMENT-MAJOR: 16x32 subtile s at byte s*1024; lane l's
// bf16x8 fragment at s*1024 + l*16 (matches global_load_lds linear write).
// ===========================================================================
#define AFRAG(bb, mi, ks) (*(const bf16x8*)(smb + (bb) + ((mi) << 11) + ((ks) << 10) + lb))
#define BFRAG(bb, nj, ks) (*(const bf16x8*)(smb + (bb) + 32768 + ((nj) << 11) + ((ks) << 10) + lb))

#define LOAD_A(bb, qm) \
  fa[0][0] = AFRAG(bb, wm8 + (qm)*4 + 0, 0); fa[0][1] = AFRAG(bb, wm8 + (qm)*4 + 0, 1); \
  fa[1][0] = AFRAG(bb, wm8 + (qm)*4 + 1, 0); fa[1][1] = AFRAG(bb, wm8 + (qm)*4 + 1, 1); \
  fa[2][0] = AFRAG(bb, wm8 + (qm)*4 + 2, 0); fa[2][1] = AFRAG(bb, wm8 + (qm)*4 + 2, 1); \
  fa[3][0] = AFRAG(bb, wm8 + (qm)*4 + 3, 0); fa[3][1] = AFRAG(bb, wm8 + (qm)*4 + 3, 1);

#define LOAD_B(bb, qn) \
  fb[(qn)*2+0][0] = BFRAG(bb, wn4 + (qn)*2 + 0, 0); fb[(qn)*2+0][1] = BFRAG(bb, wn4 + (qn)*2 + 0, 1); \
  fb[(qn)*2+1][0] = BFRAG(bb, wn4 + (qn)*2 + 1, 0); fb[(qn)*2+1][1] = BFRAG(bb, wn4 + (qn)*2 + 1, 1);

#define MM(mi, nj) \
  acc[mi][nj] = __builtin_amdgcn_mfma_f32_16x16x32_bf16(fa[(mi)&3][0], fb[nj][0], acc[mi][nj], 0, 0, 0); \
  acc[mi][nj] = __builtin_amdgcn_mfma_f32_16x16x32_bf16(fa[(mi)&3][1], fb[nj][1], acc[mi][nj], 0, 0, 0);

#define MFMA_QUAD(qm, qn) \
  MM((qm)*4+0, (qn)*2+0) MM((qm)*4+0, (qn)*2+1) \
  MM((qm)*4+1, (qn)*2+0) MM((qm)*4+1, (qn)*2+1) \
  MM((qm)*4+2, (qn)*2+0) MM((qm)*4+2, (qn)*2+1) \
  MM((qm)*4+3, (qn)*2+0) MM((qm)*4+3, (qn)*2+1)

#define PH_MFMA(qm, qn) \
  __builtin_amdgcn_s_barrier(); \
  asm volatile("s_waitcnt lgkmcnt(0)" ::: "memory"); \
  __builtin_amdgcn_sched_barrier(0); \
  __builtin_amdgcn_s_setprio(1); \
  MFMA_QUAD(qm, qn); \
  __builtin_amdgcn_s_setprio(0); \
  __builtin_amdgcn_sched_barrier(0); \
  __builtin_amdgcn_s_barrier();

__global__ __launch_bounds__(512, 2)
void gemm256(const unsigned short* __restrict__ A,
             const unsigned short* __restrict__ B,
             const float* __restrict__ bias,
             unsigned short* __restrict__ C16,
             float* __restrict__ C32,
             int K, int lda, int ldc, int n_limit, int act, int nb)
{
  __shared__ __attribute__((aligned(16))) unsigned short sm[65536];  // 128 KiB
  char* smb = (char*)sm;

  const int tid  = threadIdx.x;
  const int wave = tid >> 6, lane = tid & 63;
  const int l16 = lane & 15, quad = lane >> 4;
  const int lb = lane << 4;
  const int wm = wave >> 2, wn = wave & 3;     // 2 (M) x 4 (N)
  const int wm8 = wm * 8, wn4 = wn * 4;

  // T1: bijective XCD swizzle (m204) on flattened grid
  const int nwg  = (int)gridDim.x;
  const int orig = (int)blockIdx.x;
  const int qq = nwg >> 3, rr = nwg & 7;
  const int xcd = orig & 7, loc = orig >> 3;
  const int wgid = (xcd < rr ? xcd * (qq + 1) : rr * (qq + 1) + (xcd - rr) * qq) + loc;
  const int bx = wgid / nb, by = wgid % nb;

  const unsigned short* Ab = A + (size_t)bx * 256 * lda;
  const unsigned short* Bb = B + (size_t)by * 256 * K;

  // staging source pattern: wave w, load j -> subtile s=j*8+w of a 16KB half.
  // rows: (w>>1)*16 + j*64 + l16 ; cols: (w&1)*32 + quad*8
  const int rb0 = ((wave >> 1) << 4) + l16;
  const int cb0 = ((wave & 1) << 5) + (quad << 3);

  const int T = K >> 6;

  auto stageHalf = [&](int bufbyte, int h, int t) {
    const unsigned short* src;
    size_t ld;
    if (h < 2) { ld = (size_t)lda; src = Ab + (size_t)((h & 1) * 128 + rb0) * ld + (size_t)t * 64 + cb0; }
    else       { ld = (size_t)K;   src = Bb + (size_t)((h & 1) * 128 + rb0) * ld + (size_t)t * 64 + cb0; }
    char* dst = smb + bufbyte + h * 16384 + wave * 1024;
    stage16(src, dst);
    stage16(src + 64 * ld, dst + 8192);
  };

  bf16x8 fa[4][2], fb[4][2];
  f32x4 acc[8][4] = {};

  // prologue: tile 0 fully, tile 1 half 0
  stageHalf(0, 0, 0); stageHalf(0, 1, 0); stageHalf(0, 2, 0); stageHalf(0, 3, 0);
  if (T > 1) {
    stageHalf(1 << 16, 0, 1);
    asm volatile("s_waitcnt vmcnt(2)" ::: "memory");
  } else {
    asm volatile("s_waitcnt vmcnt(0)" ::: "memory");
  }
  __builtin_amdgcn_sched_barrier(0);
  __builtin_amdgcn_s_barrier();

  for (int t = 0; t < T; ++t) {
    const int bb  = (t & 1) << 16;
    const int nbb = bb ^ (1 << 16);
    const bool st1 = (t + 1 < T), st2 = (t + 2 < T);

    // ---- phase 1: quad (0,0); reads A[qm0] + B[qn0]; stage t+1 half1
    LOAD_A(bb, 0)
    LOAD_B(bb, 0)
    if (st1) stageHalf(nbb, 1, t + 1);
    PH_MFMA(0, 0)

    // ---- phase 2: quad (0,1); reads B[qn1]; stage t+1 half2
    LOAD_B(bb, 1)
    if (st1) stageHalf(nbb, 2, t + 1);
    PH_MFMA(0, 1)

    // ---- phase 3: quad (1,1); reads A[qm1]; stage t+1 half3
    LOAD_A(bb, 1)
    if (st1) stageHalf(nbb, 3, t + 1);
    PH_MFMA(1, 1)

    // ---- phase 4: quad (1,0); no ds_reads; stage t+2 half0; CHECKPOINT
    if (st2) {
      stageHalf(bb, 0, t + 2);
      asm volatile("s_waitcnt vmcnt(2)" ::: "memory");   // t+1 fully landed
    } else {
      asm volatile("s_waitcnt vmcnt(0)" ::: "memory");
    }
    __builtin_amdgcn_sched_barrier(0);
    __builtin_amdgcn_s_barrier();
    __builtin_amdgcn_s_setprio(1);
    MFMA_QUAD(1, 0)
    __builtin_amdgcn_s_setprio(0);
    __builtin_amdgcn_sched_barrier(0);
    __builtin_amdgcn_s_barrier();
  }

  // epilogue
  const int row0 = bx * 256 + wm * 128 + quad * 4;
  const int col0 = by * 256 + wn * 64 + l16;
#pragma unroll
  for (int nj = 0; nj < 4; ++nj) {
    const int col = col0 + nj * 16;
    if (col >= n_limit) continue;
    const float bv = bias ? bias[col] : 0.0f;
    const bool sig = (act == 2) || (act == 3 && col < 2048);
#pragma unroll
    for (int mi = 0; mi < 8; ++mi) {
#pragma unroll
      for (int r = 0; r < 4; ++r) {
        const int row = row0 + mi * 16 + r;
        float v = acc[mi][nj][r] + bv;
        if (act == 1) v = fmaxf(v, 0.0f);
        else if (sig) v = 1.0f / (1.0f + __expf(-v));
        if (C32) C32[(size_t)row * ldc + col] = v;
        if (C16) C16[(size_t)row * ldc + col] = f2bf(v);
      }
    }
  }
}

// ===========================================================================
// Flow attention, grid-parallel decomposition. Q,K,V share row stride ld.
// bh = b*16+h in [0,64); per-(b,h) slice base = b*L*ld + h*64.
// ===========================================================================

// ---- A1: ksum/qsum partials over 256-row chunks. grid(64,8), block 256.
__global__ __launch_bounds__(256)
void fa_sums(const unsigned short* __restrict__ Q, const unsigned short* __restrict__ K,
             int ld, float* __restrict__ ksp, float* __restrict__ qsp)
{
  const int bh = blockIdx.x, chunk = blockIdx.y;
  const size_t base = ((size_t)(bh >> 4) * L_SEQ) * ld + (size_t)(bh & 15) * 64;
  const int t = threadIdx.x, lane = t & 63, wave = t >> 6;
  __shared__ float red[256];
  float ks = 0.f, qs = 0.f;
  const int l0 = chunk * 256 + wave * 64;
  for (int i = 0; i < 64; i++) {
    const size_t idx = base + (size_t)(l0 + i) * ld + lane;
    ks += bf2f(K[idx]);
    qs += bf2f(Q[idx]);
  }
  red[t] = ks; __syncthreads();
  if (t < 64) ksp[(bh * 8 + chunk) * 64 + t] = red[t] + red[t + 64] + red[t + 128] + red[t + 192];
  __syncthreads();
  red[t] = qs; __syncthreads();
  if (t < 64) qsp[(bh * 8 + chunk) * 64 + t] = red[t] + red[t + 64] + red[t + 128] + red[t + 192];
}

// ---- A2+A3: per-row nr, nc; accumulate t1=sum k*nc, t2=sum q*nr partials.
__global__ __launch_bounds__(256)
void fa_rows1(const unsigned short* __restrict__ Q, const unsigned short* __restrict__ K,
              int ld, const float* __restrict__ ksp, const float* __restrict__ qsp,
              float* __restrict__ nr, float* __restrict__ t1p, float* __restrict__ t2p)
{
  const int bh = blockIdx.x, chunk = blockIdx.y;
  const size_t base = ((size_t)(bh >> 4) * L_SEQ) * ld + (size_t)(bh & 15) * 64;
  const int t = threadIdx.x, lane = t & 63, wave = t >> 6;
  const float eps = 1e-6f;
  __shared__ float s_kse[64], s_qse[64], red[256];
  if (t < 64) {
    float s = 0.f;
    for (int j = 0; j < 8; j++) s += ksp[(bh * 8 + j) * 64 + t];
    s_kse[t] = s + eps;
  } else if (t < 128) {
    const int d = t - 64;
    float s = 0.f;
    for (int j = 0; j < 8; j++) s += qsp[(bh * 8 + j) * 64 + d];
    s_qse[d] = s + eps;
  }
  __syncthreads();
  const float kse = s_kse[lane], qse = s_qse[lane];
  float t1a = 0.f, t2a = 0.f;
  for (int i = 0; i < 32; i++) {
    const int l = chunk * 128 + wave + 4 * i;
    const size_t idx = base + (size_t)l * ld + lane;
    const float q = bf2f(Q[idx]), k = bf2f(K[idx]);
    float a = (q + eps) * kse;
    float c = (k + eps) * qse;
#pragma unroll
    for (int off = 32; off; off >>= 1) { a += __shfl_xor(a, off); c += __shfl_xor(c, off); }
    const float nrl = 1.f / a, ncl = 1.f / c;
    if (lane == 0) nr[bh * L_SEQ + l] = nrl;
    t1a += k * ncl;
    t2a += q * nrl;
  }
  red[t] = t1a; __syncthreads();
  if (t < 64) t1p[(bh * 16 + chunk) * 64 + t] = red[t] + red[t + 64] + red[t + 128] + red[t + 192];
  __syncthreads();
  red[t] = t2a; __syncthreads();
  if (t < 64) t2p[(bh * 16 + chunk) * 64 + t] = red[t] + red[t + 64] + red[t + 128] + red[t + 192];
}

// ---- A4: per-row nrr (folded into nr) and raw ncr score. grid(64,16).
__global__ __launch_bounds__(256)
void fa_rows2(const unsigned short* __restrict__ Q, const unsigned short* __restrict__ K,
              int ld, const float* __restrict__ t1p, const float* __restrict__ t2p,
              float* __restrict__ nr, float* __restrict__ sc)
{
  const int bh = blockIdx.x, chunk = blockIdx.y;
  const size_t base = ((size_t)(bh >> 4) * L_SEQ) * ld + (size_t)(bh & 15) * 64;
  const int t = threadIdx.x, lane = t & 63, wave = t >> 6;
  const float eps = 1e-6f;
  __shared__ float s_t1e[64], s_t2e[64];
  if (t < 64) {
    float s = 0.f;
    for (int j = 0; j < 16; j++) s += t1p[(bh * 16 + j) * 64 + t];
    s_t1e[t] = s + eps;
  } else if (t < 128) {
    const int d = t - 64;
    float s = 0.f;
    for (int j = 0; j < 16; j++) s += t2p[(bh * 16 + j) * 64 + d];
    s_t2e[d] = s + eps;
  }
  __syncthreads();
  const float t1e = s_t1e[lane], t2e = s_t2e[lane];
  for (int i = 0; i < 32; i++) {
    const int l = chunk * 128 + wave + 4 * i;
    const size_t idx = base + (size_t)l * ld + lane;
    const float q = bf2f(Q[idx]), k = bf2f(K[idx]);
    float a = (q + eps) * t1e;
    float c = (k + eps) * t2e;
#pragma unroll
    for (int off = 32; off; off >>= 1) { a += __shfl_xor(a, off); c += __shfl_xor(c, off); }
    if (lane == 0) {
      nr[bh * L_SEQ + l] *= 1.f / (1.f + __expf(-a));
      sc[bh * L_SEQ + l] = c;
    }
  }
}

// ---- A5: softmax over L per bh, writes ncr into sc; zeroes kv[bh]. grid(64).
__global__ __launch_bounds__(256)
void fa_softmax(float* __restrict__ sc, float* __restrict__ kv)
{
  const int bh = blockIdx.x, t = threadIdx.x;
  __shared__ float red[256];
  float4* kvz = (float4*)(kv + bh * 64 * 64);
  for (int j = 0; j < 4; j++) kvz[t + 256 * j] = make_float4(0.f, 0.f, 0.f, 0.f);

  float* row = sc + bh * L_SEQ;
  float m = -3.4e38f;
  for (int l = t; l < L_SEQ; l += 256) m = fmaxf(m, row[l]);
  red[t] = m; __syncthreads();
  for (int s = 128; s > 0; s >>= 1) { if (t < s) red[t] = fmaxf(red[t], red[t + s]); __syncthreads(); }
  const float mx = red[0];
  __syncthreads();
  float ps = 0.f;
  float pv[8];
#pragma unroll
  for (int j = 0; j < 8; j++) {
    const int l = t + 256 * j;
    pv[j] = __expf(row[l] - mx);
    ps += pv[j];
  }
  red[t] = ps; __syncthreads();
  for (int s = 128; s > 0; s >>= 1) { if (t < s) red[t] += red[t + s]; __syncthreads(); }
  const float scale = (float)L_SEQ / red[0];
#pragma unroll
  for (int j = 0; j < 8; j++) row[t + 256 * j] = pv[j] * scale;
}

// ---- A6: kv[d][e] += sum_l k[l,d]*(v[l,e]*ncr[l]) over 128-row chunk (MFMA).
__global__ __launch_bounds__(256)
void fa_kv(const unsigned short* __restrict__ K, const unsigned short* __restrict__ V,
           int ld, const float* __restrict__ sc, float* __restrict__ kv)
{
  const int bh = blockIdx.x, chunk = blockIdx.y;
  const size_t base = ((size_t)(bh >> 4) * L_SEQ) * ld + (size_t)(bh & 15) * 64;
  const int t = threadIdx.x, lane = t & 63, wave = t >> 6;
  const int l16 = lane & 15, quad = lane >> 4;
  __shared__ __attribute__((aligned(16))) unsigned short s_kT[64 * 72];
  __shared__ __attribute__((aligned(16))) unsigned short s_vT[64 * 72];

  f32x4 acc5[4] = {};
  for (int sub = 0; sub < 2; sub++) {
    const int l0 = chunk * 128 + sub * 64;
#pragma unroll
    for (int it = 0; it < 4; it++) {
      const int task = it * 256 + t;     // 0..1023
      const int l = task >> 4;           // 0..63
      const int g = task & 15;           // d-group of 4
      const size_t gidx = base + (size_t)(l0 + l) * ld + g * 4;
      const ushort4 k4 = *(const ushort4*)(K + gidx);
      const ushort4 v4 = *(const ushort4*)(V + gidx);
      const float wgt = sc[bh * L_SEQ + l0 + l];
      s_kT[(g * 4 + 0) * 72 + l] = k4.x;
      s_kT[(g * 4 + 1) * 72 + l] = k4.y;
      s_kT[(g * 4 + 2) * 72 + l] = k4.z;
      s_kT[(g * 4 + 3) * 72 + l] = k4.w;
      s_vT[(g * 4 + 0) * 72 + l] = f2bf(bf2f(v4.x) * wgt);
      s_vT[(g * 4 + 1) * 72 + l] = f2bf(bf2f(v4.y) * wgt);
      s_vT[(g * 4 + 2) * 72 + l] = f2bf(bf2f(v4.z) * wgt);
      s_vT[(g * 4 + 3) * 72 + l] = f2bf(bf2f(v4.w) * wgt);
    }
    __syncthreads();
#pragma unroll
    for (int ks = 0; ks < 2; ks++) {
      const bf16x8 af = *(const bf16x8*)&s_kT[(wave * 16 + l16) * 72 + ks * 32 + quad * 8];
#pragma unroll
      for (int et = 0; et < 4; et++) {
        const bf16x8 bf = *(const bf16x8*)&s_vT[(et * 16 + l16) * 72 + ks * 32 + quad * 8];
        acc5[et] = __builtin_amdgcn_mfma_f32_16x16x32_bf16(af, bf, acc5[et], 0, 0, 0);
      }
    }
    __syncthreads();
  }
#pragma unroll
  for (int et = 0; et < 4; et++)
#pragma unroll
    for (int r = 0; r < 4; r++)
      atomicAdd(&kv[bh * 4096 + (wave * 16 + quad * 4 + r) * 64 + et * 16 + l16], acc5[et][r]);
}

// ---- A7: O[l][e] = (sum_d q[l,d]*kv[d,e]) * nr'[l]. grid(64,16), block 256.
__global__ __launch_bounds__(256)
void fa_out(const unsigned short* __restrict__ Q, int ld, const float* __restrict__ kv,
            const float* __restrict__ nr, unsigned short* O)
{
  const int bh = blockIdx.x, chunk = blockIdx.y;
  const size_t base = ((size_t)(bh >> 4) * L_SEQ) * ld + (size_t)(bh & 15) * 64;
  const int t = threadIdx.x, lane = t & 63, wave = t >> 6;
  const int l16 = lane & 15, quad = lane >> 4;
  __shared__ __attribute__((aligned(16))) unsigned short s_kvT[64 * 72];  // [e][d]

#pragma unroll
  for (int j = 0; j < 16; j++) {
    const int i = t + 256 * j;       // i = d*64 + e
    const int d = i >> 6, e = i & 63;
    s_kvT[e * 72 + d] = f2bf(kv[bh * 4096 + i]);
  }
  __syncthreads();

  bf16x8 bfr6[4][2];
#pragma unroll
  for (int et = 0; et < 4; et++)
#pragma unroll
    for (int ks = 0; ks < 2; ks++)
      bfr6[et][ks] = *(const bf16x8*)&s_kvT[(et * 16 + l16) * 72 + ks * 32 + quad * 8];

#pragma unroll
  for (int ti = 0; ti < 2; ti++) {
    const int l0 = chunk * 128 + (wave * 2 + ti) * 16;
    f32x4 oc[4] = {};
#pragma unroll
    for (int ks = 0; ks < 2; ks++) {
      const bf16x8 aq = *(const bf16x8*)(Q + base + (size_t)(l0 + l16) * ld + ks * 32 + quad * 8);
#pragma unroll
      for (int et = 0; et < 4; et++)
        oc[et] = __builtin_amdgcn_mfma_f32_16x16x32_bf16(aq, bfr6[et][ks], oc[et], 0, 0, 0);
    }
#pragma unroll
    for (int r = 0; r < 4; r++) {
      const int l = l0 + quad * 4 + r;
      const float scl = nr[bh * L_SEQ + l];
#pragma unroll
      for (int et = 0; et < 4; et++)
        O[base + (size_t)l * ld + et * 16 + l16] = f2bf(oc[et][r] * scl);
    }
  }
}

// ---------------------------------------------------------------------------
// LayerNorm over last dim (1024): out = LN(res (+ add)) * w + b. 1 wave/row.
// ---------------------------------------------------------------------------
__global__ __launch_bounds__(256)
void ln_fused(const float* res, const float* __restrict__ add,
              const float* __restrict__ w, const float* __restrict__ bb,
              float* out32, unsigned short* out16)
{
  const int row = blockIdx.x * 4 + (threadIdx.x >> 6);
  const int lane = threadIdx.x & 63;
  const size_t roff = (size_t)row * DM;
  const float4* rp = (const float4*)(res + roff);
  const float4* ap = add ? (const float4*)(add + roff) : nullptr;

  float x[16], s = 0.f, s2 = 0.f;
#pragma unroll
  for (int q4 = 0; q4 < 4; q4++) {
    float4 v = rp[lane * 4 + q4];
    if (ap) { float4 a = ap[lane * 4 + q4]; v.x += a.x; v.y += a.y; v.z += a.z; v.w += a.w; }
    x[q4 * 4 + 0] = v.x; x[q4 * 4 + 1] = v.y; x[q4 * 4 + 2] = v.z; x[q4 * 4 + 3] = v.w;
    s += v.x + v.y + v.z + v.w;
    s2 += v.x * v.x + v.y * v.y + v.z * v.z + v.w * v.w;
  }
#pragma unroll
  for (int off = 32; off; off >>= 1) { s += __shfl_xor(s, off); s2 += __shfl_xor(s2, off); }
  const float mean = s * (1.f / DM);
  const float var = s2 * (1.f / DM) - mean * mean;
  const float rstd = rsqrtf(var + 1e-5f);
#pragma unroll
  for (int j = 0; j < 16; j++) {
    const int c = lane * 16 + j;
    x[j] = (x[j] - mean) * rstd * w[c] + bb[c];
  }
  if (out32) {
    float4* op = (float4*)(out32 + roff);
#pragma unroll
    for (int q4 = 0; q4 < 4; q4++) {
      float4 v; v.x = x[q4*4+0]; v.y = x[q4*4+1]; v.z = x[q4*4+2]; v.w = x[q4*4+3];
      op[lane * 4 + q4] = v;
    }
  }
  if (out16) {
#pragma unroll
    for (int q4 = 0; q4 < 4; q4++) {
      ushort4 u;
      u.x = f2bf(x[q4*4+0]); u.y = f2bf(x[q4*4+1]); u.z = f2bf(x[q4*4+2]); u.w = f2bf(x[q4*4+3]);
      *(ushort4*)(out16 + roff + lane * 16 + q4 * 4) = u;
    }
  }
}

// ---------------------------------------------------------------------------
// Channel attention helpers
// ---------------------------------------------------------------------------
__global__ void ca_zero(float* __restrict__ ybar) {
  const int i = blockIdx.x * 256 + threadIdx.x;
  if (i < NB * DM) ybar[i] = 0.f;
}
__global__ void ca_mean(const unsigned short* __restrict__ H16, float* __restrict__ ybar) {
  const int b = blockIdx.x, cc = blockIdx.y, lc = blockIdx.z;
  const int c = cc * 256 + threadIdx.x;
  float s = 0.f;
  for (int l = lc * 256; l < lc * 256 + 256; l++)
    s += bf2f(H16[((size_t)(b * L_SEQ + l)) * DM + c]);
  atomicAdd(&ybar[b * DM + c], s);
}
__global__ void ca_gate(const float* __restrict__ ybar, const float* __restrict__ cw,
                        float* __restrict__ gate) {
  const int i = blockIdx.x * 256 + threadIdx.x;
  if (i >= NB * DM) return;
  const int b = i >> 10, c = i & 1023;
  float acc = 0.f;
#pragma unroll
  for (int j = 0; j < 5; j++) {
    const int cc = c + j - 2;
    const float yv = (cc >= 0 && cc < DM) ? ybar[b * DM + cc] * (1.f / L_SEQ) : 0.f;
    acc += cw[j] * yv;
  }
  gate[i] = 1.f / (1.f + __expf(-acc));
}
__global__ void ca_apply(float* __restrict__ H32, unsigned short* __restrict__ H16,
                         const float* __restrict__ gate) {
  const size_t i = ((size_t)blockIdx.x * 256 + threadIdx.x) * 4;
  const int row = (int)(i >> 10);
  const int b = row >> 11;
  const int c = (int)(i & 1023);
  float4 v = *(float4*)(H32 + i);
  v.x *= gate[b * DM + c + 0];
  v.y *= gate[b * DM + c + 1];
  v.z *= gate[b * DM + c + 2];
  v.w *= gate[b * DM + c + 3];
  *(float4*)(H32 + i) = v;
  unsigned short* hp = H16 + i;
  hp[0] = f2bf(v.x); hp[1] = f2bf(v.y); hp[2] = f2bf(v.z); hp[3] = f2bf(v.w);
}

// ---------------------------------------------------------------------------
// f32 -> bf16 conversions
// ---------------------------------------------------------------------------
__global__ void embed_gather(const float* __restrict__ x, unsigned short* __restrict__ Ae) {
  const int i = blockIdx.x * 256 + threadIdx.x;
  if (i >= ROWS * 192) return;
  const int row = i / 192, kk = i % 192;
  const int t3 = kk >> 6, c = kk & 63;
  const int b = row >> 11, l = row & 2047;
  const int ls = (l + t3 - 1 + L_SEQ) & 2047;
  Ae[i] = f2bf(x[((size_t)(b * L_SEQ + ls)) * 64 + c]);
}
__global__ void embed_repack(const float* __restrict__ w, unsigned short* __restrict__ We) {
  const int i = blockIdx.x * 256 + threadIdx.x;
  if (i >= DM * 192) return;
  const int f = i / 192, kk = i % 192;
  const int t3 = kk >> 6, c = kk & 63;
  We[i] = f2bf(w[(f * 64 + c) * 3 + t3]);
}
__global__ void pad_proj(const float* __restrict__ pw, unsigned short* __restrict__ Wp) {
  const int i = blockIdx.x * 256 + threadIdx.x;
  if (i >= 128 * DM) return;
  Wp[i] = ((i >> 10) < 64) ? f2bf(pw[i]) : (unsigned short)0;
}
__global__ void pack_qkv_bias(const float* __restrict__ bq, const float* __restrict__ bk,
                              const float* __restrict__ bv, float* __restrict__ bqkv) {
  const int i = blockIdx.x * 256 + threadIdx.x;   // 0..3071
  if (i >= 3072) return;
  bqkv[i] = (i < 1024) ? bq[i] : (i < 2048 ? bk[i - 1024] : bv[i - 2048]);
}
// 12M scalar elements as 3M float4s: [0,4M): Wq/Wk/Wv/Wo (1M each); [4M,12M): c1,c2 (4M each)
__global__ void cvt_layer_weights(const float* __restrict__ Wq, const float* __restrict__ Wk,
                                  const float* __restrict__ Wv, const float* __restrict__ Wo,
                                  const float* __restrict__ c1, const float* __restrict__ c2,
                                  unsigned short* __restrict__ Wl, unsigned short* __restrict__ WlFF) {
  const int g = blockIdx.x * 256 + threadIdx.x;   // 0..3M-1 float4 units
  const int i = g << 2;                           // scalar index
  const float* src; unsigned short* dst;
  if (i < (1 << 22)) {
    const int w = i >> 20, off = i & ((1 << 20) - 1);
    const float* srcs[4] = {Wq, Wk, Wv, Wo};
    src = srcs[w] + off; dst = Wl + (w << 20) + off;
  } else {
    const int j = i - (1 << 22);
    const int w = j >> 22, off = j & ((1 << 22) - 1);
    src = (w ? c2 : c1) + off; dst = WlFF + (w << 22) + off;
  }
  const float4 v = *(const float4*)src;
  ushort4 u; u.x = f2bf(v.x); u.y = f2bf(v.y); u.z = f2bf(v.z); u.w = f2bf(v.w);
  *(ushort4*)dst = u;
}

// ---------------------------------------------------------------------------
extern "C" void kernel_launch(void* const* d_in, const int* in_sizes, int n_in,
                              void* d_out, int out_size, void* d_ws, size_t ws_size,
                              hipStream_t stream) {
  const float* x     = (const float*)d_in[0];
  const float* tokw  = (const float*)d_in[1];
  const float* Wq    = (const float*)d_in[2];
  const float* bq    = (const float*)d_in[3];
  const float* Wk    = (const float*)d_in[4];
  const float* bk    = (const float*)d_in[5];
  const float* Wv    = (const float*)d_in[6];
  const float* bv    = (const float*)d_in[7];
  const float* Wo    = (const float*)d_in[8];
  const float* bo    = (const float*)d_in[9];
  const float* c1w   = (const float*)d_in[10];
  const float* c1b   = (const float*)d_in[11];
  const float* c2w   = (const float*)d_in[12];
  const float* c2b   = (const float*)d_in[13];
  const float* ln1w  = (const float*)d_in[14];
  const float* ln1b  = (const float*)d_in[15];
  const float* ln2w  = (const float*)d_in[16];
  const float* ln2b  = (const float*)d_in[17];
  const float* caw   = (const float*)d_in[18];
  const float* lnfw  = (const float*)d_in[19];
  const float* lnfb  = (const float*)d_in[20];
  const float* projw = (const float*)d_in[21];
  const float* projb = (const float*)d_in[22];

  char* ws = (char*)d_ws;
  float*          R32 = (float*)(ws);                               // 32 MB
  unsigned short* R16 = (unsigned short*)(ws + ((size_t)32 << 20)); // 16 MB
  float*          A32 = (float*)(ws + ((size_t)48 << 20));          // 32 MB
  unsigned short* U   = (unsigned short*)(ws + ((size_t)80 << 20)); // 64 MB
  unsigned short* QKV16 = U;                       // 48 MB: [8192][3072] (Q|K|V cols)
  unsigned short* F16   = U;                       // 64 MB (FFN phase)
  char* fa = ws + ((size_t)128 << 20);
  float* fa_nr  = (float*)(fa);                    // 512 KB [64][2048]
  float* fa_sc  = (float*)(fa + (512 << 10));      // 512 KB [64][2048]
  float* fa_ksp = (float*)(fa + (1024 << 10));     // 128 KB [64][8][64]
  float* fa_qsp = (float*)(fa + (1152 << 10));     // 128 KB
  float* fa_t1p = (float*)(fa + (1280 << 10));     // 512 KB [64][16][64]
  float* fa_t2p = (float*)(fa + (1792 << 10));     // 512 KB
  float* fa_kvb = (float*)(fa + (2304 << 10));     // 1 MB  [64][64][64]
  unsigned short* Wl   = (unsigned short*)(ws + ((size_t)144 << 20)); // 8 MB  [Wq|Wk|Wv|Wo]
  unsigned short* WlFF = (unsigned short*)(ws + ((size_t)152 << 20)); // 16 MB [c1|c2]
  char* misc = ws + ((size_t)168 << 20);
  float*          ybar = (float*)misc;                              // 16 KB
  float*          gate = (float*)(misc + (16 << 10));               // 16 KB
  float*          bqkv = (float*)(misc + (32 << 10));               // 12 KB
  unsigned short* We   = (unsigned short*)(misc + (64 << 10));      // 384 KB
  unsigned short* Wp   = (unsigned short*)(misc + (512 << 10));     // 256 KB

  const int BIG = 1 << 30;
  auto gemm = [&](const unsigned short* A, const unsigned short* B, const float* bias,
                  unsigned short* C16, float* C32, int N, int K, int lda, int ldc,
                  int nlim, int act) {
    if ((N & 255) == 0 && (K & 63) == 0) {
      const int nb = N >> 8;
      const int nwg = (ROWS >> 8) * nb;
      gemm256<<<dim3(nwg), dim3(512), 0, stream>>>(A, B, bias, C16, C32, K, lda, ldc, nlim, act, nb);
    } else {
      dim3 grid(ROWS / 128, N / 128);
      gemm_bt<<<grid, dim3(256), 0, stream>>>(A, B, bias, C16, C32, K, lda, ldc, nlim, act);
    }
  };

  // ---- token embedding (circular conv k=3 as im2col GEMM) -> R (f32 + bf16)
  embed_gather<<<(ROWS * 192 + 255) / 256, 256, 0, stream>>>(x, U);
  embed_repack<<<(DM * 192 + 255) / 256, 256, 0, stream>>>(tokw, We);
  gemm(U, We, nullptr, R16, R32, DM, 192, 192, DM, BIG, 0);

  // ---- 4 encoder layers (+CA), then layer 3 re-applied (faithful to reference)
  for (int it = 0; it < 5; it++) {
    const int i = (it < 4) ? it : 3;
    if (it != 4) {  // it==4 reuses layer-3 weights/bias already converted at it==3
      cvt_layer_weights<<<(3 << 20) / 256, 256, 0, stream>>>(
          Wq + ((size_t)i << 20), Wk + ((size_t)i << 20),
          Wv + ((size_t)i << 20), Wo + ((size_t)i << 20),
          c1w + ((size_t)i << 22), c2w + ((size_t)i << 22), Wl, WlFF);
      pack_qkv_bias<<<12, 256, 0, stream>>>(bq + i * DM, bk + i * DM, bv + i * DM, bqkv);
    }
    const unsigned short* Wo16 = Wl + (3 << 20);
    const unsigned short* C116 = WlFF;
    const unsigned short* C216 = WlFF + (1 << 22);

    // fused QKV GEMM: N=3072, sigmoid on Q,K columns (<2048) only
    gemm(R16, Wl, bqkv, QKV16, nullptr, 3072, DM, DM, 3072, BIG, 3);

    const unsigned short* Qp = QKV16;
    const unsigned short* Kp = QKV16 + 1024;
    unsigned short*       Vp = QKV16 + 2048;   // O written in place over V

    fa_sums   <<<dim3(64, 8),  256, 0, stream>>>(Qp, Kp, 3072, fa_ksp, fa_qsp);
    fa_rows1  <<<dim3(64, 16), 256, 0, stream>>>(Qp, Kp, 3072, fa_ksp, fa_qsp, fa_nr, fa_t1p, fa_t2p);
    fa_rows2  <<<dim3(64, 16), 256, 0, stream>>>(Qp, Kp, 3072, fa_t1p, fa_t2p, fa_nr, fa_sc);
    fa_softmax<<<dim3(64),     256, 0, stream>>>(fa_sc, fa_kvb);
    fa_kv     <<<dim3(64, 16), 256, 0, stream>>>(Kp, Vp, 3072, fa_sc, fa_kvb);
    fa_out    <<<dim3(64, 16), 256, 0, stream>>>(Qp, 3072, fa_kvb, fa_nr, Vp);

    gemm(Vp, Wo16, bo + i * DM, nullptr, A32, DM, DM, 3072, DM, BIG, 0);
    ln_fused<<<ROWS / 4, 256, 0, stream>>>(R32, A32, ln1w + i * DM, ln1b + i * DM, R32, R16);
    gemm(R16, C116, c1b + i * DFF, F16, nullptr, DFF, DM, DM, DFF, BIG, 1); // relu
    gemm(F16, C216, c2b + i * DM, nullptr, A32, DM, DFF, DFF, DM, BIG, 0);
    ln_fused<<<ROWS / 4, 256, 0, stream>>>(R32, A32, ln2w + i * DM, ln2b + i * DM, R32, R16);

    if (it < 4) {
      ca_zero<<<16, 256, 0, stream>>>(ybar);
      ca_mean<<<dim3(NB, 4, 8), 256, 0, stream>>>(R16, ybar);
      ca_gate<<<16, 256, 0, stream>>>(ybar, caw + i * 5, gate);
      ca_apply<<<(ROWS * DM / 4) / 256, 256, 0, stream>>>(R32, R16, gate);
    }
  }

  // ---- final LN + projection to C_OUT=64 (padded weight, guarded f32 stores)
  ln_fused<<<ROWS / 4, 256, 0, stream>>>(R32, nullptr, lnfw, lnfb, nullptr, U);
  pad_proj<<<(128 * DM + 255) / 256, 256, 0, stream>>>(projw, Wp);
  gemm(U, Wp, projb, nullptr, (float*)d_out, 128, DM, DM, 64, 64, 0);

  (void)in_sizes; (void)n_in; (void)out_size; (void)ws_size;
}

// Round 2
// 3008.691 us; speedup vs baseline: 1.0500x; 1.0500x over previous
//
#include <hip/hip_runtime.h>
#include <stdint.h>

#define L_SEQ 2048
#define DM 1024
#define NH 16
#define DFF 4096
#define NB 4
#define ROWS (NB * L_SEQ)   // 8192

typedef __attribute__((ext_vector_type(8))) __bf16 bf16x8;
typedef __attribute__((ext_vector_type(4))) float f32x4;

__device__ __forceinline__ float bf2f(unsigned short u) {
  union { unsigned int i; float f; } x; x.i = ((unsigned int)u) << 16; return x.f;
}
__device__ __forceinline__ unsigned short f2bf(float f) {
  union { float f; unsigned int i; } x; x.f = f;
  unsigned int r = x.i + 0x7FFFu + ((x.i >> 16) & 1u);
  return (unsigned short)(r >> 16);
}

typedef __attribute__((address_space(3))) void lds_void;
typedef const __attribute__((address_space(1))) void gbl_void;

// Forced global_load_lds (gfx950): lane i's 16 bytes land at base + i*16.
__device__ __forceinline__ void stage16(const void* g, void* ldsbase) {
  __builtin_amdgcn_global_load_lds((gbl_void*)g, (lds_void*)ldsbase, 16, 0, 0);
}

#define MFMA1(d, a, b) (d) = __builtin_amdgcn_mfma_f32_16x16x32_bf16((a), (b), (d), 0, 0, 0)

// ===========================================================================
// 256x256x64 4-phase pipelined GEMM. C = A[8192,K] * B[N,K]^T.
// 8 waves (2M x 4N), LDS 2 x 64KB double buffer, fragment-major subtiles.
// Stage schedule (T4): ALL stages for tile t+2 issue at ph3 (B, after B's
// last reader closed at ph2 barrier) and ph4 (A, closed at ph3 barrier).
// Checkpoint at end of iter t: vmcnt(8) -> waits only loads issued in
// iter t-1 (4 phases ago, ~1600cy > HBM latency). Never drains in loop.
// ===========================================================================
#define AFRAG(bb, mi, ks) (*(const bf16x8*)(smb + (bb) + ((mi) << 11) + ((ks) << 10) + lb))
#define BFRAG(bb, nj, ks) (*(const bf16x8*)(smb + (bb) + 32768 + ((nj) << 11) + ((ks) << 10) + lb))

#define LOAD_A(bb, qm) \
  fa[0][0] = AFRAG(bb, wm8 + (qm)*4 + 0, 0); fa[0][1] = AFRAG(bb, wm8 + (qm)*4 + 0, 1); \
  fa[1][0] = AFRAG(bb, wm8 + (qm)*4 + 1, 0); fa[1][1] = AFRAG(bb, wm8 + (qm)*4 + 1, 1); \
  fa[2][0] = AFRAG(bb, wm8 + (qm)*4 + 2, 0); fa[2][1] = AFRAG(bb, wm8 + (qm)*4 + 2, 1); \
  fa[3][0] = AFRAG(bb, wm8 + (qm)*4 + 3, 0); fa[3][1] = AFRAG(bb, wm8 + (qm)*4 + 3, 1);

#define LOAD_B(bb, qn) \
  fb[(qn)*2+0][0] = BFRAG(bb, wn4 + (qn)*2 + 0, 0); fb[(qn)*2+0][1] = BFRAG(bb, wn4 + (qn)*2 + 0, 1); \
  fb[(qn)*2+1][0] = BFRAG(bb, wn4 + (qn)*2 + 1, 0); fb[(qn)*2+1][1] = BFRAG(bb, wn4 + (qn)*2 + 1, 1);

#define MM(mi, nj) \
  acc[mi][nj] = __builtin_amdgcn_mfma_f32_16x16x32_bf16(fa[(mi)&3][0], fb[nj][0], acc[mi][nj], 0, 0, 0); \
  acc[mi][nj] = __builtin_amdgcn_mfma_f32_16x16x32_bf16(fa[(mi)&3][1], fb[nj][1], acc[mi][nj], 0, 0, 0);

#define MFMA_QUAD(qm, qn) \
  MM((qm)*4+0, (qn)*2+0) MM((qm)*4+0, (qn)*2+1) \
  MM((qm)*4+1, (qn)*2+0) MM((qm)*4+1, (qn)*2+1) \
  MM((qm)*4+2, (qn)*2+0) MM((qm)*4+2, (qn)*2+1) \
  MM((qm)*4+3, (qn)*2+0) MM((qm)*4+3, (qn)*2+1)

#define PH_OPEN \
  __builtin_amdgcn_s_barrier(); \
  asm volatile("s_waitcnt lgkmcnt(0)" ::: "memory"); \
  __builtin_amdgcn_sched_barrier(0); \
  __builtin_amdgcn_s_setprio(1);

#define PH_CLOSE \
  __builtin_amdgcn_s_setprio(0); \
  __builtin_amdgcn_sched_barrier(0); \
  __builtin_amdgcn_s_barrier();

__global__ __launch_bounds__(512, 2)
void gemm256(const unsigned short* __restrict__ A,
             const unsigned short* __restrict__ B,
             const float* __restrict__ bias,
             unsigned short* __restrict__ C16,
             float* __restrict__ C32,
             int K, int lda, int ldc, int n_limit, int act, int nb)
{
  __shared__ __attribute__((aligned(16))) unsigned short sm[65536];  // 128 KiB
  char* smb = (char*)sm;

  const int tid  = threadIdx.x;
  const int wave = tid >> 6, lane = tid & 63;
  const int l16 = lane & 15, quad = lane >> 4;
  const int lb = lane << 4;
  const int wm = wave >> 2, wn = wave & 3;     // 2 (M) x 4 (N)
  const int wm8 = wm * 8, wn4 = wn * 4;

  // T1: bijective XCD swizzle (m204) on flattened grid
  const int nwg  = (int)gridDim.x;
  const int orig = (int)blockIdx.x;
  const int qq = nwg >> 3, rr = nwg & 7;
  const int xcd = orig & 7, loc = orig >> 3;
  const int wgid = (xcd < rr ? xcd * (qq + 1) : rr * (qq + 1) + (xcd - rr) * qq) + loc;
  const int bx = wgid / nb, by = wgid % nb;

  const unsigned short* Ab = A + (size_t)bx * 256 * lda;
  const unsigned short* Bb = B + (size_t)by * 256 * K;

  // staging source pattern: wave w, load j -> subtile s=j*8+w of a 16KB half.
  const int rb0 = ((wave >> 1) << 4) + l16;
  const int cb0 = ((wave & 1) << 5) + (quad << 3);

  const int T = K >> 6;

  auto stageHalf = [&](int bufbyte, int h, int t) {
    const unsigned short* src;
    size_t ld;
    if (h < 2) { ld = (size_t)lda; src = Ab + (size_t)((h & 1) * 128 + rb0) * ld + (size_t)t * 64 + cb0; }
    else       { ld = (size_t)K;   src = Bb + (size_t)((h & 1) * 128 + rb0) * ld + (size_t)t * 64 + cb0; }
    char* dst = smb + bufbyte + h * 16384 + wave * 1024;
    stage16(src, dst);
    stage16(src + 64 * ld, dst + 8192);
  };

  bf16x8 fa[4][2], fb[4][2];
  f32x4 acc[8][4] = {};

  // prologue: tile 0 -> buf0, tile 1 -> buf1; wait only tile 0 (vmcnt(8)).
  stageHalf(0, 0, 0); stageHalf(0, 1, 0); stageHalf(0, 2, 0); stageHalf(0, 3, 0);
  if (T > 1) {
    stageHalf(1 << 16, 0, 1); stageHalf(1 << 16, 1, 1);
    stageHalf(1 << 16, 2, 1); stageHalf(1 << 16, 3, 1);
    asm volatile("s_waitcnt vmcnt(8)" ::: "memory");
  } else {
    asm volatile("s_waitcnt vmcnt(0)" ::: "memory");
  }
  __builtin_amdgcn_sched_barrier(0);
  __builtin_amdgcn_s_barrier();

  for (int t = 0; t < T; ++t) {
    const int bb = (t & 1) << 16;
    const bool st2 = (t + 2 < T);

    // ---- phase 1: quad (0,0)
    LOAD_A(bb, 0)
    LOAD_B(bb, 0)
    PH_OPEN
    MFMA_QUAD(0, 0)
    PH_CLOSE

    // ---- phase 2: quad (0,1); last B reads of tile t
    LOAD_B(bb, 1)
    PH_OPEN
    MFMA_QUAD(0, 1)
    PH_CLOSE

    // ---- phase 3: quad (1,1); last A reads; stage B(t+2) into bb (B closed)
    LOAD_A(bb, 1)
    if (st2) { stageHalf(bb, 2, t + 2); stageHalf(bb, 3, t + 2); }
    PH_OPEN
    MFMA_QUAD(1, 1)
    PH_CLOSE

    // ---- phase 4: quad (1,0); no ds_reads; stage A(t+2); counted checkpoint
    if (st2) {
      stageHalf(bb, 0, t + 2); stageHalf(bb, 1, t + 2);
      asm volatile("s_waitcnt vmcnt(8)" ::: "memory");   // tile t+1 landed; t+2 in flight
    } else {
      asm volatile("s_waitcnt vmcnt(0)" ::: "memory");
    }
    __builtin_amdgcn_sched_barrier(0);
    __builtin_amdgcn_s_barrier();
    __builtin_amdgcn_s_setprio(1);
    MFMA_QUAD(1, 0)
    PH_CLOSE
  }

  // epilogue
  const int row0 = bx * 256 + wm * 128 + quad * 4;
  const int col0 = by * 256 + wn * 64 + l16;
#pragma unroll
  for (int nj = 0; nj < 4; ++nj) {
    const int col = col0 + nj * 16;
    if (col >= n_limit) continue;
    const float bv = bias ? bias[col] : 0.0f;
    const bool sig = (act == 2) || (act == 3 && col < 2048);
#pragma unroll
    for (int mi = 0; mi < 8; ++mi) {
#pragma unroll
      for (int r = 0; r < 4; ++r) {
        const int row = row0 + mi * 16 + r;
        float v = acc[mi][nj][r] + bv;
        if (act == 1) v = fmaxf(v, 0.0f);
        else if (sig) v = 1.0f / (1.0f + __expf(-v));
        if (C32) C32[(size_t)row * ldc + col] = v;
        if (C16) C16[(size_t)row * ldc + col] = f2bf(v);
      }
    }
  }
}

// ===========================================================================
// 128x128x64 4-phase pipelined GEMM, 4 waves (2M x 2N), 64 KiB LDS
// -> 2 blocks/CU resident (inter-block latency hiding). Same fragment-major
// layout and counted-vmcnt schedule as gemm256. For N-small GEMMs where
// 256-tiles would under-fill the grid (N=1024: 512 WGs vs 128).
// ===========================================================================
#define AFRAG1(bb, mig, ks) (*(const bf16x8*)(smb + (bb) + (((mig) * 2 + (ks)) << 10) + lb))
#define BFRAG1(bb, njg, ks) (*(const bf16x8*)(smb + (bb) + 16384 + (((njg) * 2 + (ks)) << 10) + lb))

#define PH128(...) \
  __builtin_amdgcn_s_barrier(); \
  asm volatile("s_waitcnt lgkmcnt(0)" ::: "memory"); \
  __builtin_amdgcn_sched_barrier(0); \
  __builtin_amdgcn_s_setprio(1); \
  __VA_ARGS__ \
  __builtin_amdgcn_s_setprio(0); \
  __builtin_amdgcn_sched_barrier(0); \
  __builtin_amdgcn_s_barrier();

__global__ __launch_bounds__(256, 2)
void gemm128(const unsigned short* __restrict__ A,
             const unsigned short* __restrict__ B,
             const float* __restrict__ bias,
             unsigned short* __restrict__ C16,
             float* __restrict__ C32,
             int K, int lda, int ldc, int n_limit, int act, int nb)
{
  __shared__ __attribute__((aligned(16))) unsigned short sm[32768];  // 64 KiB
  char* smb = (char*)sm;
  const int tid  = threadIdx.x;
  const int wave = tid >> 6, lane = tid & 63;
  const int l16 = lane & 15, quad = lane >> 4;
  const int lb = lane << 4;
  const int wm = wave >> 1, wn = wave & 1;      // 2 (M) x 2 (N), 64x64 per wave
  const int wm4 = wm * 4, wn4 = wn * 4;

  const int nwg  = (int)gridDim.x;
  const int orig = (int)blockIdx.x;
  const int qq = nwg >> 3, rr = nwg & 7;
  const int xcd = orig & 7, loc = orig >> 3;
  const int wgid = (xcd < rr ? xcd * (qq + 1) : rr * (qq + 1) + (xcd - rr) * qq) + loc;
  const int bx = wgid / nb, by = wgid % nb;

  const unsigned short* Ab = A + (size_t)bx * 128 * lda;
  const unsigned short* Bb = B + (size_t)by * 128 * K;

  // staging: thread tid, part e -> subtile s = e*4 + wave, lane l = tid&63.
  // row = e*32 + (wave>>1)*16 + l16 ; col = (wave&1)*32 + quad*8  (col fixed)
  const int rb0 = ((wave >> 1) << 4) + l16;
  const int cb0 = ((wave & 1) << 5) + (quad << 3);

  const int T = K >> 6;

  auto stageA = [&](int bufbyte, int t) {
    const unsigned short* s0 = Ab + (size_t)rb0 * lda + (size_t)t * 64 + cb0;
    char* d = smb + bufbyte + wave * 1024;
    stage16(s0, d);
    stage16(s0 + (size_t)32 * lda, d + 4096);
    stage16(s0 + (size_t)64 * lda, d + 8192);
    stage16(s0 + (size_t)96 * lda, d + 12288);
  };
  auto stageB = [&](int bufbyte, int t) {
    const unsigned short* s0 = Bb + (size_t)rb0 * K + (size_t)t * 64 + cb0;
    char* d = smb + bufbyte + 16384 + wave * 1024;
    stage16(s0, d);
    stage16(s0 + (size_t)32 * K, d + 4096);
    stage16(s0 + (size_t)64 * K, d + 8192);
    stage16(s0 + (size_t)96 * K, d + 12288);
  };

  bf16x8 fa[2][2], fb01[2][2], fb23[2][2];
  f32x4 acc[4][4] = {};

  // prologue
  stageA(0, 0); stageB(0, 0);
  if (T > 1) {
    stageA(32768, 1); stageB(32768, 1);
    asm volatile("s_waitcnt vmcnt(8)" ::: "memory");
  } else {
    asm volatile("s_waitcnt vmcnt(0)" ::: "memory");
  }
  __builtin_amdgcn_sched_barrier(0);
  __builtin_amdgcn_s_barrier();

  for (int t = 0; t < T; ++t) {
    const int bb = (t & 1) << 15;
    const bool st2 = (t + 2 < T);

    // ---- ph1: mi01 x nj01
    fa[0][0] = AFRAG1(bb, wm4 + 0, 0); fa[0][1] = AFRAG1(bb, wm4 + 0, 1);
    fa[1][0] = AFRAG1(bb, wm4 + 1, 0); fa[1][1] = AFRAG1(bb, wm4 + 1, 1);
    fb01[0][0] = BFRAG1(bb, wn4 + 0, 0); fb01[0][1] = BFRAG1(bb, wn4 + 0, 1);
    fb01[1][0] = BFRAG1(bb, wn4 + 1, 0); fb01[1][1] = BFRAG1(bb, wn4 + 1, 1);
    PH128(
      MFMA1(acc[0][0], fa[0][0], fb01[0][0]); MFMA1(acc[0][0], fa[0][1], fb01[0][1]);
      MFMA1(acc[0][1], fa[0][0], fb01[1][0]); MFMA1(acc[0][1], fa[0][1], fb01[1][1]);
      MFMA1(acc[1][0], fa[1][0], fb01[0][0]); MFMA1(acc[1][0], fa[1][1], fb01[0][1]);
      MFMA1(acc[1][1], fa[1][0], fb01[1][0]); MFMA1(acc[1][1], fa[1][1], fb01[1][1]);
    )

    // ---- ph2: mi01 x nj23; last B reads of tile t
    fb23[0][0] = BFRAG1(bb, wn4 + 2, 0); fb23[0][1] = BFRAG1(bb, wn4 + 2, 1);
    fb23[1][0] = BFRAG1(bb, wn4 + 3, 0); fb23[1][1] = BFRAG1(bb, wn4 + 3, 1);
    PH128(
      MFMA1(acc[0][2], fa[0][0], fb23[0][0]); MFMA1(acc[0][2], fa[0][1], fb23[0][1]);
      MFMA1(acc[0][3], fa[0][0], fb23[1][0]); MFMA1(acc[0][3], fa[0][1], fb23[1][1]);
      MFMA1(acc[1][2], fa[1][0], fb23[0][0]); MFMA1(acc[1][2], fa[1][1], fb23[0][1]);
      MFMA1(acc[1][3], fa[1][0], fb23[1][0]); MFMA1(acc[1][3], fa[1][1], fb23[1][1]);
    )

    // ---- ph3: mi23 x nj23; last A reads; stage B(t+2)
    fa[0][0] = AFRAG1(bb, wm4 + 2, 0); fa[0][1] = AFRAG1(bb, wm4 + 2, 1);
    fa[1][0] = AFRAG1(bb, wm4 + 3, 0); fa[1][1] = AFRAG1(bb, wm4 + 3, 1);
    if (st2) stageB(bb, t + 2);
    PH128(
      MFMA1(acc[2][2], fa[0][0], fb23[0][0]); MFMA1(acc[2][2], fa[0][1], fb23[0][1]);
      MFMA1(acc[2][3], fa[0][0], fb23[1][0]); MFMA1(acc[2][3], fa[0][1], fb23[1][1]);
      MFMA1(acc[3][2], fa[1][0], fb23[0][0]); MFMA1(acc[3][2], fa[1][1], fb23[0][1]);
      MFMA1(acc[3][3], fa[1][0], fb23[1][0]); MFMA1(acc[3][3], fa[1][1], fb23[1][1]);
    )

    // ---- ph4: mi23 x nj01; stage A(t+2); counted checkpoint
    if (st2) {
      stageA(bb, t + 2);
      asm volatile("s_waitcnt vmcnt(8)" ::: "memory");
    } else {
      asm volatile("s_waitcnt vmcnt(0)" ::: "memory");
    }
    PH128(
      MFMA1(acc[2][0], fa[0][0], fb01[0][0]); MFMA1(acc[2][0], fa[0][1], fb01[0][1]);
      MFMA1(acc[2][1], fa[0][0], fb01[1][0]); MFMA1(acc[2][1], fa[0][1], fb01[1][1]);
      MFMA1(acc[3][0], fa[1][0], fb01[0][0]); MFMA1(acc[3][0], fa[1][1], fb01[0][1]);
      MFMA1(acc[3][1], fa[1][0], fb01[1][0]); MFMA1(acc[3][1], fa[1][1], fb01[1][1]);
    )
  }

  // epilogue
  const int row0 = bx * 128 + wm * 64 + quad * 4;
  const int col0 = by * 128 + wn * 64 + l16;
#pragma unroll
  for (int nj = 0; nj < 4; ++nj) {
    const int col = col0 + nj * 16;
    if (col >= n_limit) continue;
    const float bv = bias ? bias[col] : 0.0f;
    const bool sig = (act == 2) || (act == 3 && col < 2048);
#pragma unroll
    for (int mi = 0; mi < 4; ++mi) {
#pragma unroll
      for (int r = 0; r < 4; ++r) {
        const int row = row0 + mi * 16 + r;
        float v = acc[mi][nj][r] + bv;
        if (act == 1) v = fmaxf(v, 0.0f);
        else if (sig) v = 1.0f / (1.0f + __expf(-v));
        if (C32) C32[(size_t)row * ldc + col] = v;
        if (C16) C16[(size_t)row * ldc + col] = f2bf(v);
      }
    }
  }
}

// ===========================================================================
// Flow attention, grid-parallel decomposition. Q,K,V share row stride ld.
// bh = b*16+h in [0,64); per-(b,h) slice base = b*L*ld + h*64.
// ===========================================================================

// ---- A1: ksum/qsum partials over 256-row chunks. grid(64,8), block 256.
__global__ __launch_bounds__(256)
void fa_sums(const unsigned short* __restrict__ Q, const unsigned short* __restrict__ K,
             int ld, float* __restrict__ ksp, float* __restrict__ qsp)
{
  const int bh = blockIdx.x, chunk = blockIdx.y;
  const size_t base = ((size_t)(bh >> 4) * L_SEQ) * ld + (size_t)(bh & 15) * 64;
  const int t = threadIdx.x, lane = t & 63, wave = t >> 6;
  __shared__ float red[256];
  float ks = 0.f, qs = 0.f;
  const int l0 = chunk * 256 + wave * 64;
  for (int i = 0; i < 64; i++) {
    const size_t idx = base + (size_t)(l0 + i) * ld + lane;
    ks += bf2f(K[idx]);
    qs += bf2f(Q[idx]);
  }
  red[t] = ks; __syncthreads();
  if (t < 64) ksp[(bh * 8 + chunk) * 64 + t] = red[t] + red[t + 64] + red[t + 128] + red[t + 192];
  __syncthreads();
  red[t] = qs; __syncthreads();
  if (t < 64) qsp[(bh * 8 + chunk) * 64 + t] = red[t] + red[t + 64] + red[t + 128] + red[t + 192];
}

// ---- A2+A3: per-row nr, nc; accumulate t1=sum k*nc, t2=sum q*nr partials.
__global__ __launch_bounds__(256)
void fa_rows1(const unsigned short* __restrict__ Q, const unsigned short* __restrict__ K,
              int ld, const float* __restrict__ ksp, const float* __restrict__ qsp,
              float* __restrict__ nr, float* __restrict__ t1p, float* __restrict__ t2p)
{
  const int bh = blockIdx.x, chunk = blockIdx.y;
  const size_t base = ((size_t)(bh >> 4) * L_SEQ) * ld + (size_t)(bh & 15) * 64;
  const int t = threadIdx.x, lane = t & 63, wave = t >> 6;
  const float eps = 1e-6f;
  __shared__ float s_kse[64], s_qse[64], red[256];
  if (t < 64) {
    float s = 0.f;
    for (int j = 0; j < 8; j++) s += ksp[(bh * 8 + j) * 64 + t];
    s_kse[t] = s + eps;
  } else if (t < 128) {
    const int d = t - 64;
    float s = 0.f;
    for (int j = 0; j < 8; j++) s += qsp[(bh * 8 + j) * 64 + d];
    s_qse[d] = s + eps;
  }
  __syncthreads();
  const float kse = s_kse[lane], qse = s_qse[lane];
  float t1a = 0.f, t2a = 0.f;
  for (int i = 0; i < 32; i++) {
    const int l = chunk * 128 + wave + 4 * i;
    const size_t idx = base + (size_t)l * ld + lane;
    const float q = bf2f(Q[idx]), k = bf2f(K[idx]);
    float a = (q + eps) * kse;
    float c = (k + eps) * qse;
#pragma unroll
    for (int off = 32; off; off >>= 1) { a += __shfl_xor(a, off); c += __shfl_xor(c, off); }
    const float nrl = 1.f / a, ncl = 1.f / c;
    if (lane == 0) nr[bh * L_SEQ + l] = nrl;
    t1a += k * ncl;
    t2a += q * nrl;
  }
  red[t] = t1a; __syncthreads();
  if (t < 64) t1p[(bh * 16 + chunk) * 64 + t] = red[t] + red[t + 64] + red[t + 128] + red[t + 192];
  __syncthreads();
  red[t] = t2a; __syncthreads();
  if (t < 64) t2p[(bh * 16 + chunk) * 64 + t] = red[t] + red[t + 64] + red[t + 128] + red[t + 192];
}

// ---- A4: per-row nrr (folded into nr) and raw ncr score. grid(64,16).
__global__ __launch_bounds__(256)
void fa_rows2(const unsigned short* __restrict__ Q, const unsigned short* __restrict__ K,
              int ld, const float* __restrict__ t1p, const float* __restrict__ t2p,
              float* __restrict__ nr, float* __restrict__ sc)
{
  const int bh = blockIdx.x, chunk = blockIdx.y;
  const size_t base = ((size_t)(bh >> 4) * L_SEQ) * ld + (size_t)(bh & 15) * 64;
  const int t = threadIdx.x, lane = t & 63, wave = t >> 6;
  const float eps = 1e-6f;
  __shared__ float s_t1e[64], s_t2e[64];
  if (t < 64) {
    float s = 0.f;
    for (int j = 0; j < 16; j++) s += t1p[(bh * 16 + j) * 64 + t];
    s_t1e[t] = s + eps;
  } else if (t < 128) {
    const int d = t - 64;
    float s = 0.f;
    for (int j = 0; j < 16; j++) s += t2p[(bh * 16 + j) * 64 + d];
    s_t2e[d] = s + eps;
  }
  __syncthreads();
  const float t1e = s_t1e[lane], t2e = s_t2e[lane];
  for (int i = 0; i < 32; i++) {
    const int l = chunk * 128 + wave + 4 * i;
    const size_t idx = base + (size_t)l * ld + lane;
    const float q = bf2f(Q[idx]), k = bf2f(K[idx]);
    float a = (q + eps) * t1e;
    float c = (k + eps) * t2e;
#pragma unroll
    for (int off = 32; off; off >>= 1) { a += __shfl_xor(a, off); c += __shfl_xor(c, off); }
    if (lane == 0) {
      nr[bh * L_SEQ + l] *= 1.f / (1.f + __expf(-a));
      sc[bh * L_SEQ + l] = c;
    }
  }
}

// ---- A5: softmax over L per bh, writes ncr into sc; zeroes kv[bh]. grid(64).
__global__ __launch_bounds__(256)
void fa_softmax(float* __restrict__ sc, float* __restrict__ kv)
{
  const int bh = blockIdx.x, t = threadIdx.x;
  __shared__ float red[256];
  float4* kvz = (float4*)(kv + bh * 64 * 64);
  for (int j = 0; j < 4; j++) kvz[t + 256 * j] = make_float4(0.f, 0.f, 0.f, 0.f);

  float* row = sc + bh * L_SEQ;
  float m = -3.4e38f;
  for (int l = t; l < L_SEQ; l += 256) m = fmaxf(m, row[l]);
  red[t] = m; __syncthreads();
  for (int s = 128; s > 0; s >>= 1) { if (t < s) red[t] = fmaxf(red[t], red[t + s]); __syncthreads(); }
  const float mx = red[0];
  __syncthreads();
  float ps = 0.f;
  float pv[8];
#pragma unroll
  for (int j = 0; j < 8; j++) {
    const int l = t + 256 * j;
    pv[j] = __expf(row[l] - mx);
    ps += pv[j];
  }
  red[t] = ps; __syncthreads();
  for (int s = 128; s > 0; s >>= 1) { if (t < s) red[t] += red[t + s]; __syncthreads(); }
  const float scale = (float)L_SEQ / red[0];
#pragma unroll
  for (int j = 0; j < 8; j++) row[t + 256 * j] = pv[j] * scale;
}

// ---- A6: kv[d][e] += sum_l k[l,d]*(v[l,e]*ncr[l]) over 128-row chunk (MFMA).
__global__ __launch_bounds__(256)
void fa_kv(const unsigned short* __restrict__ K, const unsigned short* __restrict__ V,
           int ld, const float* __restrict__ sc, float* __restrict__ kv)
{
  const int bh = blockIdx.x, chunk = blockIdx.y;
  const size_t base = ((size_t)(bh >> 4) * L_SEQ) * ld + (size_t)(bh & 15) * 64;
  const int t = threadIdx.x, lane = t & 63, wave = t >> 6;
  const int l16 = lane & 15, quad = lane >> 4;
  __shared__ __attribute__((aligned(16))) unsigned short s_kT[64 * 72];
  __shared__ __attribute__((aligned(16))) unsigned short s_vT[64 * 72];

  f32x4 acc5[4] = {};
  for (int sub = 0; sub < 2; sub++) {
    const int l0 = chunk * 128 + sub * 64;
#pragma unroll
    for (int it = 0; it < 4; it++) {
      const int task = it * 256 + t;     // 0..1023
      const int l = task >> 4;           // 0..63
      const int g = task & 15;           // d-group of 4
      const size_t gidx = base + (size_t)(l0 + l) * ld + g * 4;
      const ushort4 k4 = *(const ushort4*)(K + gidx);
      const ushort4 v4 = *(const ushort4*)(V + gidx);
      const float wgt = sc[bh * L_SEQ + l0 + l];
      s_kT[(g * 4 + 0) * 72 + l] = k4.x;
      s_kT[(g * 4 + 1) * 72 + l] = k4.y;
      s_kT[(g * 4 + 2) * 72 + l] = k4.z;
      s_kT[(g * 4 + 3) * 72 + l] = k4.w;
      s_vT[(g * 4 + 0) * 72 + l] = f2bf(bf2f(v4.x) * wgt);
      s_vT[(g * 4 + 1) * 72 + l] = f2bf(bf2f(v4.y) * wgt);
      s_vT[(g * 4 + 2) * 72 + l] = f2bf(bf2f(v4.z) * wgt);
      s_vT[(g * 4 + 3) * 72 + l] = f2bf(bf2f(v4.w) * wgt);
    }
    __syncthreads();
#pragma unroll
    for (int ks = 0; ks < 2; ks++) {
      const bf16x8 af = *(const bf16x8*)&s_kT[(wave * 16 + l16) * 72 + ks * 32 + quad * 8];
#pragma unroll
      for (int et = 0; et < 4; et++) {
        const bf16x8 bf = *(const bf16x8*)&s_vT[(et * 16 + l16) * 72 + ks * 32 + quad * 8];
        acc5[et] = __builtin_amdgcn_mfma_f32_16x16x32_bf16(af, bf, acc5[et], 0, 0, 0);
      }
    }
    __syncthreads();
  }
#pragma unroll
  for (int et = 0; et < 4; et++)
#pragma unroll
    for (int r = 0; r < 4; r++)
      atomicAdd(&kv[bh * 4096 + (wave * 16 + quad * 4 + r) * 64 + et * 16 + l16], acc5[et][r]);
}

// ---- A7: O[l][e] = (sum_d q[l,d]*kv[d,e]) * nr'[l]. grid(64,16), block 256.
__global__ __launch_bounds__(256)
void fa_out(const unsigned short* __restrict__ Q, int ld, const float* __restrict__ kv,
            const float* __restrict__ nr, unsigned short* O)
{
  const int bh = blockIdx.x, chunk = blockIdx.y;
  const size_t base = ((size_t)(bh >> 4) * L_SEQ) * ld + (size_t)(bh & 15) * 64;
  const int t = threadIdx.x, lane = t & 63, wave = t >> 6;
  const int l16 = lane & 15, quad = lane >> 4;
  __shared__ __attribute__((aligned(16))) unsigned short s_kvT[64 * 72];  // [e][d]

#pragma unroll
  for (int j = 0; j < 16; j++) {
    const int i = t + 256 * j;       // i = d*64 + e
    const int d = i >> 6, e = i & 63;
    s_kvT[e * 72 + d] = f2bf(kv[bh * 4096 + i]);
  }
  __syncthreads();

  bf16x8 bfr6[4][2];
#pragma unroll
  for (int et = 0; et < 4; et++)
#pragma unroll
    for (int ks = 0; ks < 2; ks++)
      bfr6[et][ks] = *(const bf16x8*)&s_kvT[(et * 16 + l16) * 72 + ks * 32 + quad * 8];

#pragma unroll
  for (int ti = 0; ti < 2; ti++) {
    const int l0 = chunk * 128 + (wave * 2 + ti) * 16;
    f32x4 oc[4] = {};
#pragma unroll
    for (int ks = 0; ks < 2; ks++) {
      const bf16x8 aq = *(const bf16x8*)(Q + base + (size_t)(l0 + l16) * ld + ks * 32 + quad * 8);
#pragma unroll
      for (int et = 0; et < 4; et++)
        oc[et] = __builtin_amdgcn_mfma_f32_16x16x32_bf16(aq, bfr6[et][ks], oc[et], 0, 0, 0);
    }
#pragma unroll
    for (int r = 0; r < 4; r++) {
      const int l = l0 + quad * 4 + r;
      const float scl = nr[bh * L_SEQ + l];
#pragma unroll
      for (int et = 0; et < 4; et++)
        O[base + (size_t)l * ld + et * 16 + l16] = f2bf(oc[et][r] * scl);
    }
  }
}

// ---------------------------------------------------------------------------
// LayerNorm over last dim (1024): out = LN(res (+ add)) * w + b. 1 wave/row.
// ---------------------------------------------------------------------------
__global__ __launch_bounds__(256)
void ln_fused(const float* res, const float* __restrict__ add,
              const float* __restrict__ w, const float* __restrict__ bb,
              float* out32, unsigned short* out16)
{
  const int row = blockIdx.x * 4 + (threadIdx.x >> 6);
  const int lane = threadIdx.x & 63;
  const size_t roff = (size_t)row * DM;
  const float4* rp = (const float4*)(res + roff);
  const float4* ap = add ? (const float4*)(add + roff) : nullptr;

  float x[16], s = 0.f, s2 = 0.f;
#pragma unroll
  for (int q4 = 0; q4 < 4; q4++) {
    float4 v = rp[lane * 4 + q4];
    if (ap) { float4 a = ap[lane * 4 + q4]; v.x += a.x; v.y += a.y; v.z += a.z; v.w += a.w; }
    x[q4 * 4 + 0] = v.x; x[q4 * 4 + 1] = v.y; x[q4 * 4 + 2] = v.z; x[q4 * 4 + 3] = v.w;
    s += v.x + v.y + v.z + v.w;
    s2 += v.x * v.x + v.y * v.y + v.z * v.z + v.w * v.w;
  }
#pragma unroll
  for (int off = 32; off; off >>= 1) { s += __shfl_xor(s, off); s2 += __shfl_xor(s2, off); }
  const float mean = s * (1.f / DM);
  const float var = s2 * (1.f / DM) - mean * mean;
  const float rstd = rsqrtf(var + 1e-5f);
#pragma unroll
  for (int j = 0; j < 16; j++) {
    const int c = lane * 16 + j;
    x[j] = (x[j] - mean) * rstd * w[c] + bb[c];
  }
  if (out32) {
    float4* op = (float4*)(out32 + roff);
#pragma unroll
    for (int q4 = 0; q4 < 4; q4++) {
      float4 v; v.x = x[q4*4+0]; v.y = x[q4*4+1]; v.z = x[q4*4+2]; v.w = x[q4*4+3];
      op[lane * 4 + q4] = v;
    }
  }
  if (out16) {
#pragma unroll
    for (int q4 = 0; q4 < 4; q4++) {
      ushort4 u;
      u.x = f2bf(x[q4*4+0]); u.y = f2bf(x[q4*4+1]); u.z = f2bf(x[q4*4+2]); u.w = f2bf(x[q4*4+3]);
      *(ushort4*)(out16 + roff + lane * 16 + q4 * 4) = u;
    }
  }
}

// ---------------------------------------------------------------------------
// Channel attention helpers
// ---------------------------------------------------------------------------
__global__ void ca_zero(float* __restrict__ ybar) {
  const int i = blockIdx.x * 256 + threadIdx.x;
  if (i < NB * DM) ybar[i] = 0.f;
}
__global__ void ca_mean(const unsigned short* __restrict__ H16, float* __restrict__ ybar) {
  const int b = blockIdx.x, cc = blockIdx.y, lc = blockIdx.z;
  const int c = cc * 256 + threadIdx.x;
  float s = 0.f;
  for (int l = lc * 256; l < lc * 256 + 256; l++)
    s += bf2f(H16[((size_t)(b * L_SEQ + l)) * DM + c]);
  atomicAdd(&ybar[b * DM + c], s);
}
__global__ void ca_gate(const float* __restrict__ ybar, const float* __restrict__ cw,
                        float* __restrict__ gate) {
  const int i = blockIdx.x * 256 + threadIdx.x;
  if (i >= NB * DM) return;
  const int b = i >> 10, c = i & 1023;
  float acc = 0.f;
#pragma unroll
  for (int j = 0; j < 5; j++) {
    const int cc = c + j - 2;
    const float yv = (cc >= 0 && cc < DM) ? ybar[b * DM + cc] * (1.f / L_SEQ) : 0.f;
    acc += cw[j] * yv;
  }
  gate[i] = 1.f / (1.f + __expf(-acc));
}
__global__ void ca_apply(float* __restrict__ H32, unsigned short* __restrict__ H16,
                         const float* __restrict__ gate) {
  const size_t i = ((size_t)blockIdx.x * 256 + threadIdx.x) * 4;
  const int row = (int)(i >> 10);
  const int b = row >> 11;
  const int c = (int)(i & 1023);
  float4 v = *(float4*)(H32 + i);
  v.x *= gate[b * DM + c + 0];
  v.y *= gate[b * DM + c + 1];
  v.z *= gate[b * DM + c + 2];
  v.w *= gate[b * DM + c + 3];
  *(float4*)(H32 + i) = v;
  unsigned short* hp = H16 + i;
  hp[0] = f2bf(v.x); hp[1] = f2bf(v.y); hp[2] = f2bf(v.z); hp[3] = f2bf(v.w);
}

// ---------------------------------------------------------------------------
// f32 -> bf16 conversions
// ---------------------------------------------------------------------------
__global__ void embed_gather(const float* __restrict__ x, unsigned short* __restrict__ Ae) {
  const int i = blockIdx.x * 256 + threadIdx.x;
  if (i >= ROWS * 192) return;
  const int row = i / 192, kk = i % 192;
  const int t3 = kk >> 6, c = kk & 63;
  const int b = row >> 11, l = row & 2047;
  const int ls = (l + t3 - 1 + L_SEQ) & 2047;
  Ae[i] = f2bf(x[((size_t)(b * L_SEQ + ls)) * 64 + c]);
}
__global__ void embed_repack(const float* __restrict__ w, unsigned short* __restrict__ We) {
  const int i = blockIdx.x * 256 + threadIdx.x;
  if (i >= DM * 192) return;
  const int f = i / 192, kk = i % 192;
  const int t3 = kk >> 6, c = kk & 63;
  We[i] = f2bf(w[(f * 64 + c) * 3 + t3]);
}
__global__ void pad_proj(const float* __restrict__ pw, unsigned short* __restrict__ Wp) {
  const int i = blockIdx.x * 256 + threadIdx.x;
  if (i >= 128 * DM) return;
  Wp[i] = ((i >> 10) < 64) ? f2bf(pw[i]) : (unsigned short)0;
}
__global__ void pack_qkv_bias(const float* __restrict__ bq, const float* __restrict__ bk,
                              const float* __restrict__ bv, float* __restrict__ bqkv) {
  const int i = blockIdx.x * 256 + threadIdx.x;   // 0..3071
  if (i >= 3072) return;
  bqkv[i] = (i < 1024) ? bq[i] : (i < 2048 ? bk[i - 1024] : bv[i - 2048]);
}
// 12M scalar elements as 3M float4s: [0,4M): Wq/Wk/Wv/Wo (1M each); [4M,12M): c1,c2 (4M each)
__global__ void cvt_layer_weights(const float* __restrict__ Wq, const float* __restrict__ Wk,
                                  const float* __restrict__ Wv, const float* __restrict__ Wo,
                                  const float* __restrict__ c1, const float* __restrict__ c2,
                                  unsigned short* __restrict__ Wl, unsigned short* __restrict__ WlFF) {
  const int g = blockIdx.x * 256 + threadIdx.x;   // 0..3M-1 float4 units
  const int i = g << 2;                           // scalar index
  const float* src; unsigned short* dst;
  if (i < (1 << 22)) {
    const int w = i >> 20, off = i & ((1 << 20) - 1);
    const float* srcs[4] = {Wq, Wk, Wv, Wo};
    src = srcs[w] + off; dst = Wl + (w << 20) + off;
  } else {
    const int j = i - (1 << 22);
    const int w = j >> 22, off = j & ((1 << 22) - 1);
    src = (w ? c2 : c1) + off; dst = WlFF + (w << 22) + off;
  }
  const float4 v = *(const float4*)src;
  ushort4 u; u.x = f2bf(v.x); u.y = f2bf(v.y); u.z = f2bf(v.z); u.w = f2bf(v.w);
  *(ushort4*)dst = u;
}

// ---------------------------------------------------------------------------
extern "C" void kernel_launch(void* const* d_in, const int* in_sizes, int n_in,
                              void* d_out, int out_size, void* d_ws, size_t ws_size,
                              hipStream_t stream) {
  const float* x     = (const float*)d_in[0];
  const float* tokw  = (const float*)d_in[1];
  const float* Wq    = (const float*)d_in[2];
  const float* bq    = (const float*)d_in[3];
  const float* Wk    = (const float*)d_in[4];
  const float* bk    = (const float*)d_in[5];
  const float* Wv    = (const float*)d_in[6];
  const float* bv    = (const float*)d_in[7];
  const float* Wo    = (const float*)d_in[8];
  const float* bo    = (const float*)d_in[9];
  const float* c1w   = (const float*)d_in[10];
  const float* c1b   = (const float*)d_in[11];
  const float* c2w   = (const float*)d_in[12];
  const float* c2b   = (const float*)d_in[13];
  const float* ln1w  = (const float*)d_in[14];
  const float* ln1b  = (const float*)d_in[15];
  const float* ln2w  = (const float*)d_in[16];
  const float* ln2b  = (const float*)d_in[17];
  const float* caw   = (const float*)d_in[18];
  const float* lnfw  = (const float*)d_in[19];
  const float* lnfb  = (const float*)d_in[20];
  const float* projw = (const float*)d_in[21];
  const float* projb = (const float*)d_in[22];

  char* ws = (char*)d_ws;
  float*          R32 = (float*)(ws);                               // 32 MB
  unsigned short* R16 = (unsigned short*)(ws + ((size_t)32 << 20)); // 16 MB
  float*          A32 = (float*)(ws + ((size_t)48 << 20));          // 32 MB
  unsigned short* U   = (unsigned short*)(ws + ((size_t)80 << 20)); // 64 MB
  unsigned short* QKV16 = U;                       // 48 MB: [8192][3072] (Q|K|V cols)
  unsigned short* F16   = U;                       // 64 MB (FFN phase)
  char* fa = ws + ((size_t)128 << 20);
  float* fa_nr  = (float*)(fa);                    // 512 KB [64][2048]
  float* fa_sc  = (float*)(fa + (512 << 10));      // 512 KB [64][2048]
  float* fa_ksp = (float*)(fa + (1024 << 10));     // 128 KB [64][8][64]
  float* fa_qsp = (float*)(fa + (1152 << 10));     // 128 KB
  float* fa_t1p = (float*)(fa + (1280 << 10));     // 512 KB [64][16][64]
  float* fa_t2p = (float*)(fa + (1792 << 10));     // 512 KB
  float* fa_kvb = (float*)(fa + (2304 << 10));     // 1 MB  [64][64][64]
  unsigned short* Wl   = (unsigned short*)(ws + ((size_t)144 << 20)); // 8 MB  [Wq|Wk|Wv|Wo]
  unsigned short* WlFF = (unsigned short*)(ws + ((size_t)152 << 20)); // 16 MB [c1|c2]
  char* misc = ws + ((size_t)168 << 20);
  float*          ybar = (float*)misc;                              // 16 KB
  float*          gate = (float*)(misc + (16 << 10));               // 16 KB
  float*          bqkv = (float*)(misc + (32 << 10));               // 12 KB
  unsigned short* We   = (unsigned short*)(misc + (64 << 10));      // 384 KB
  unsigned short* Wp   = (unsigned short*)(misc + (512 << 10));     // 256 KB

  const int BIG = 1 << 30;
  auto gemm = [&](const unsigned short* A, const unsigned short* B, const float* bias,
                  unsigned short* C16, float* C32, int N, int K, int lda, int ldc,
                  int nlim, int act) {
    if (N >= 3072) {           // 256x256 tiles (grid fills with >=384 WGs)
      const int nb = N >> 8;
      gemm256<<<dim3((ROWS >> 8) * nb), dim3(512), 0, stream>>>(
          A, B, bias, C16, C32, K, lda, ldc, nlim, act, nb);
    } else {                   // 128x128 tiles, 2 blocks/CU (N=1024 -> 512 WGs)
      const int nb = N >> 7;
      gemm128<<<dim3((ROWS >> 7) * nb), dim3(256), 0, stream>>>(
          A, B, bias, C16, C32, K, lda, ldc, nlim, act, nb);
    }
  };

  // ---- token embedding (circular conv k=3 as im2col GEMM) -> R (f32 + bf16)
  embed_gather<<<(ROWS * 192 + 255) / 256, 256, 0, stream>>>(x, U);
  embed_repack<<<(DM * 192 + 255) / 256, 256, 0, stream>>>(tokw, We);
  gemm(U, We, nullptr, R16, R32, DM, 192, 192, DM, BIG, 0);

  // ---- 4 encoder layers (+CA), then layer 3 re-applied (faithful to reference)
  for (int it = 0; it < 5; it++) {
    const int i = (it < 4) ? it : 3;
    if (it != 4) {  // it==4 reuses layer-3 weights/bias already converted at it==3
      cvt_layer_weights<<<(3 << 20) / 256, 256, 0, stream>>>(
          Wq + ((size_t)i << 20), Wk + ((size_t)i << 20),
          Wv + ((size_t)i << 20), Wo + ((size_t)i << 20),
          c1w + ((size_t)i << 22), c2w + ((size_t)i << 22), Wl, WlFF);
      pack_qkv_bias<<<12, 256, 0, stream>>>(bq + i * DM, bk + i * DM, bv + i * DM, bqkv);
    }
    const unsigned short* Wo16 = Wl + (3 << 20);
    const unsigned short* C116 = WlFF;
    const unsigned short* C216 = WlFF + (1 << 22);

    // fused QKV GEMM: N=3072, sigmoid on Q,K columns (<2048) only
    gemm(R16, Wl, bqkv, QKV16, nullptr, 3072, DM, DM, 3072, BIG, 3);

    const unsigned short* Qp = QKV16;
    const unsigned short* Kp = QKV16 + 1024;
    unsigned short*       Vp = QKV16 + 2048;   // O written in place over V

    fa_sums   <<<dim3(64, 8),  256, 0, stream>>>(Qp, Kp, 3072, fa_ksp, fa_qsp);
    fa_rows1  <<<dim3(64, 16), 256, 0, stream>>>(Qp, Kp, 3072, fa_ksp, fa_qsp, fa_nr, fa_t1p, fa_t2p);
    fa_rows2  <<<dim3(64, 16), 256, 0, stream>>>(Qp, Kp, 3072, fa_t1p, fa_t2p, fa_nr, fa_sc);
    fa_softmax<<<dim3(64),     256, 0, stream>>>(fa_sc, fa_kvb);
    fa_kv     <<<dim3(64, 16), 256, 0, stream>>>(Kp, Vp, 3072, fa_sc, fa_kvb);
    fa_out    <<<dim3(64, 16), 256, 0, stream>>>(Qp, 3072, fa_kvb, fa_nr, Vp);

    gemm(Vp, Wo16, bo + i * DM, nullptr, A32, DM, DM, 3072, DM, BIG, 0);
    ln_fused<<<ROWS / 4, 256, 0, stream>>>(R32, A32, ln1w + i * DM, ln1b + i * DM, R32, R16);
    gemm(R16, C116, c1b + i * DFF, F16, nullptr, DFF, DM, DM, DFF, BIG, 1); // relu
    gemm(F16, C216, c2b + i * DM, nullptr, A32, DM, DFF, DFF, DM, BIG, 0);
    ln_fused<<<ROWS / 4, 256, 0, stream>>>(R32, A32, ln2w + i * DM, ln2b + i * DM, R32, R16);

    if (it < 4) {
      ca_zero<<<16, 256, 0, stream>>>(ybar);
      ca_mean<<<dim3(NB, 4, 8), 256, 0, stream>>>(R16, ybar);
      ca_gate<<<16, 256, 0, stream>>>(ybar, caw + i * 5, gate);
      ca_apply<<<(ROWS * DM / 4) / 256, 256, 0, stream>>>(R32, R16, gate);
    }
  }

  // ---- final LN + projection to C_OUT=64 (padded weight, guarded f32 stores)
  ln_fused<<<ROWS / 4, 256, 0, stream>>>(R32, nullptr, lnfw, lnfb, nullptr, U);
  pad_proj<<<(128 * DM + 255) / 256, 256, 0, stream>>>(projw, Wp);
  gemm(U, Wp, projb, nullptr, (float*)d_out, 128, DM, DM, 64, 64, 0);

  (void)in_sizes; (void)n_in; (void)out_size; (void)ws_size;
}